// Round 1
// baseline (33549.664 us; speedup 1.0000x reference)
//
#include <hip/hip_runtime.h>
#include <cstdint>
#include <cstddef>

// ---------------------------------------------------------------------------
// BiLSTM-CRF (NER) for MI355X.
// Phases (all on `stream`, stream-ordered):
//   1. ingemm_kernel : x = emb[sent]; Gin[dir][t][2048] = x@Wih.T + bih + bhh
//   2. lstm_kernel   : persistent 64-WG kernel (32 per direction). Weights Whh
//                      pinned in VGPRs (128 fp32/thread). Per-step cross-WG
//                      sync via step-indexed flags (release/acquire, agent
//                      scope). h history written to hs[dir][t][512].
//   3. feats_kernel  : feats[t][32] = concat(hf,hb) @ W_tag.T + b_tag
//   4. viterbi_kernel: single-wave Viterbi forward + wave argmax + backtrack.
// Output: d_out[0] = path_score (f32), d_out[1..4096] = best_path as f32.
// ---------------------------------------------------------------------------

#define S_LEN 4096
#define E_DIM 300
#define HALF  512
#define G4    2048
#define TAGS  32
#define ALLT  34
#define START_T 32
#define STOP_T  33
#define NEGV  (-10000.0f)
#define WGDIR 32   // workgroups per direction in lstm_kernel

// ---------------- phase 1: embedding gather + input GEMM -------------------
#define KC 20   // 300 = 15 * 20, no tail
__global__ __launch_bounds__(256) void ingemm_kernel(
    const int* __restrict__ sent, const float* __restrict__ emb,
    const float* __restrict__ Wih_f, const float* __restrict__ bih_f, const float* __restrict__ bhh_f,
    const float* __restrict__ Wih_b, const float* __restrict__ bih_b, const float* __restrict__ bhh_b,
    float* __restrict__ Gin)
{
  __shared__ float As[64][KC + 1];
  __shared__ float Bs[64][KC + 1];
  __shared__ int sidx[64];
  const int tid = threadIdx.x;
  const int t0 = blockIdx.x * 64;     // 64 t-tiles
  const int J0 = blockIdx.y * 64;     // 64 j-tiles over 4096 (2 dirs x 2048)
  const int dir = J0 >> 11;           // uniform per block (2048/64 = 32 tiles)
  const int row0 = J0 & 2047;
  const float* __restrict__ Wsrc = dir ? Wih_b : Wih_f;
  const float* __restrict__ bi = dir ? bih_b : bih_f;
  const float* __restrict__ bh = dir ? bhh_b : bhh_f;
  if (tid < 64) sidx[tid] = sent[t0 + tid];
  __syncthreads();
  float acc[4][4] = {};
  const int ty = tid >> 4, tx = tid & 15;
  for (int kk = 0; kk < E_DIM; kk += KC) {
#pragma unroll
    for (int n = 0; n < 5; ++n) {           // 64*20 = 1280 = 5*256
      int idx = n * 256 + tid;
      int i = idx / KC, k = idx - i * KC;
      As[i][k] = emb[(size_t)sidx[i] * E_DIM + kk + k];
      Bs[i][k] = Wsrc[(size_t)(row0 + i) * E_DIM + kk + k];
    }
    __syncthreads();
#pragma unroll
    for (int k = 0; k < KC; ++k) {
      float a0 = As[ty * 4 + 0][k], a1 = As[ty * 4 + 1][k];
      float a2 = As[ty * 4 + 2][k], a3 = As[ty * 4 + 3][k];
      float b0 = Bs[tx * 4 + 0][k], b1 = Bs[tx * 4 + 1][k];
      float b2 = Bs[tx * 4 + 2][k], b3 = Bs[tx * 4 + 3][k];
      acc[0][0] += a0 * b0; acc[0][1] += a0 * b1; acc[0][2] += a0 * b2; acc[0][3] += a0 * b3;
      acc[1][0] += a1 * b0; acc[1][1] += a1 * b1; acc[1][2] += a1 * b2; acc[1][3] += a1 * b3;
      acc[2][0] += a2 * b0; acc[2][1] += a2 * b1; acc[2][2] += a2 * b2; acc[2][3] += a2 * b3;
      acc[3][0] += a3 * b0; acc[3][1] += a3 * b1; acc[3][2] += a3 * b2; acc[3][3] += a3 * b3;
    }
    __syncthreads();
  }
#pragma unroll
  for (int r = 0; r < 4; ++r)
#pragma unroll
    for (int cc = 0; cc < 4; ++cc) {
      int t = t0 + ty * 4 + r;
      int row = row0 + tx * 4 + cc;
      Gin[((size_t)dir * S_LEN + t) * G4 + row] = acc[r][cc] + bi[row] + bh[row];
    }
}

// ---------------- phase 2: persistent BiLSTM recurrence --------------------
__global__ __launch_bounds__(256) void lstm_kernel(
    const float* __restrict__ Whh_f, const float* __restrict__ Whh_b,
    const float* __restrict__ h0, const float* __restrict__ c0,
    const float* __restrict__ Gin, float* __restrict__ hs, int* __restrict__ flags)
{
  const int wg = blockIdx.x;       // 0..63
  const int dir = wg >> 5;
  const int wgd = wg & 31;         // WG index within direction; owns 16 units
  const int tid = threadIdx.x;
  const int wv = tid >> 6;         // wave 0..3: h-chunk [wv*128, wv*128+128)
  const int lane = tid & 63;       // row 0..63: gate = lane>>4, unit = lane&15
  const int gate = lane >> 4;
  const int ul = lane & 15;
  const int row = gate * HALF + wgd * 16 + ul;   // row of Whh (2048 x 512)
  const float* __restrict__ Whh = dir ? Whh_b : Whh_f;

  // pin this thread's weight slice in VGPRs for all 4096 steps
  float w[128];
  {
    const float4* wp = (const float4*)(Whh + (size_t)row * HALF + wv * 128);
#pragma unroll
    for (int i = 0; i < 32; ++i) {
      float4 v = wp[i];
      w[4 * i + 0] = v.x; w[4 * i + 1] = v.y; w[4 * i + 2] = v.z; w[4 * i + 3] = v.w;
    }
  }

  __shared__ __align__(16) float hbuf[HALF];
  __shared__ float partial[4][64];
  __shared__ float gbuf[64];

  float c = 0.f;
  if (tid < 16) c = c0[dir * HALF + wgd * 16 + tid];

  int* flg = flags + dir * S_LEN;
  float* hs_d = hs + (size_t)dir * S_LEN * HALF;
  const float* Gin_d = Gin + (size_t)dir * S_LEN * G4;

  for (int s = 0; s < S_LEN; ++s) {
    const int t = dir ? (S_LEN - 1 - s) : s;
    if (s > 0 && tid == 0) {
      while (__hip_atomic_load(&flg[s - 1], __ATOMIC_ACQUIRE, __HIP_MEMORY_SCOPE_AGENT) < WGDIR) {
        __builtin_amdgcn_s_sleep(1);
      }
    }
    __syncthreads();
    const float* hsrc = (s == 0) ? (h0 + dir * HALF)
                                 : (hs_d + (size_t)(dir ? t + 1 : t - 1) * HALF);
    {
      float a = __hip_atomic_load((const float*)&hsrc[tid], __ATOMIC_RELAXED, __HIP_MEMORY_SCOPE_AGENT);
      float b = __hip_atomic_load((const float*)&hsrc[tid + 256], __ATOMIC_RELAXED, __HIP_MEMORY_SCOPE_AGENT);
      hbuf[tid] = a;
      hbuf[tid + 256] = b;
    }
    __syncthreads();
    // partial dot: this wave's 128-chunk of h (LDS broadcast) x pinned weights
    float acc0 = 0.f, acc1 = 0.f, acc2 = 0.f, acc3 = 0.f;
    const float4* hb4 = (const float4*)(hbuf + wv * 128);
#pragma unroll
    for (int i = 0; i < 32; ++i) {
      float4 hv = hb4[i];
      acc0 += w[4 * i + 0] * hv.x;
      acc1 += w[4 * i + 1] * hv.y;
      acc2 += w[4 * i + 2] * hv.z;
      acc3 += w[4 * i + 3] * hv.w;
    }
    partial[wv][lane] = (acc0 + acc1) + (acc2 + acc3);
    __syncthreads();
    if (tid < 64) {
      float g = partial[0][tid] + partial[1][tid] + partial[2][tid] + partial[3][tid];
      const int grow = (tid >> 4) * HALF + wgd * 16 + (tid & 15);
      g += Gin_d[(size_t)t * G4 + grow];
      gbuf[tid] = g;
    }
    __syncthreads();
    if (tid < 16) {
      float gi = gbuf[tid];
      float gf = gbuf[16 + tid];
      float gg = gbuf[32 + tid];
      float go = gbuf[48 + tid];
      gi = 1.f / (1.f + expf(-gi));
      gf = 1.f / (1.f + expf(-gf));
      gg = tanhf(gg);
      go = 1.f / (1.f + expf(-go));
      c = gf * c + gi * gg;
      float hv = go * tanhf(c);
      __hip_atomic_store(&hs_d[(size_t)t * HALF + wgd * 16 + tid], hv,
                         __ATOMIC_RELAXED, __HIP_MEMORY_SCOPE_AGENT);
    }
    __threadfence();
    __syncthreads();
    if (tid == 0) {
      __hip_atomic_fetch_add(&flg[s], 1, __ATOMIC_RELEASE, __HIP_MEMORY_SCOPE_AGENT);
    }
  }
}

// ---------------- phase 3: tag feature GEMM --------------------------------
__global__ __launch_bounds__(256) void feats_kernel(
    const float* __restrict__ hs, const float* __restrict__ Wtag,
    const float* __restrict__ btag, float* __restrict__ feats)
{
  __shared__ float hc[8][257];
  __shared__ float wt[32][257];
  const int tid = threadIdx.x;
  const int t0 = blockIdx.x * 8;
  const int lt = tid >> 5, s = tid & 31;
  float acc = 0.f;
  for (int mc = 0; mc < 1024; mc += 256) {
#pragma unroll
    for (int n = 0; n < 8; ++n) {           // 8*256 elems of hcat
      int idx = n * 256 + tid;
      int r = idx >> 8, m = idx & 255;
      int gm = mc + m;
      hc[r][m] = (gm < 512) ? hs[(size_t)(t0 + r) * HALF + gm]
                            : hs[(size_t)(S_LEN + t0 + r) * HALF + (gm - 512)];
    }
#pragma unroll
    for (int n = 0; n < 32; ++n) {          // 32*256 elems of W_tag
      int idx = n * 256 + tid;
      int r = idx >> 8, m = idx & 255;
      wt[r][m] = Wtag[(size_t)r * 1024 + mc + m];
    }
    __syncthreads();
#pragma unroll 8
    for (int m = 0; m < 256; ++m) acc += hc[lt][m] * wt[s][m];
    __syncthreads();
  }
  feats[(size_t)(t0 + lt) * TAGS + s] = acc + btag[s];
}

// ---------------- phase 4: Viterbi forward + backtrack ---------------------
__global__ __launch_bounds__(64) void viterbi_kernel(
    const float* __restrict__ feats, const float* __restrict__ trans,
    int* __restrict__ bp_g, float* __restrict__ out)
{
  const int tid = threadIdx.x;   // one wave; lane s holds fv[s]
  float Trow[ALLT];
#pragma unroll
  for (int j = 0; j < ALLT; ++j)
    Trow[j] = (tid < ALLT) ? trans[tid * ALLT + j] : -1e30f;
  float fv = (tid == START_T) ? 0.f : NEGV;
  float fcur = (tid < TAGS) ? feats[tid] : NEGV;
  for (int t = 0; t < S_LEN; ++t) {
    float fnext = NEGV;
    if (t + 1 < S_LEN && tid < TAGS) fnext = feats[(size_t)(t + 1) * TAGS + tid];
    float best = -1e30f; int bj = 0;
#pragma unroll
    for (int j = 0; j < ALLT; ++j) {
      float sc = __shfl(fv, j) + Trow[j];
      if (sc > best) { best = sc; bj = j; }   // strict > keeps first argmax
    }
    if (tid < ALLT) bp_g[(size_t)t * ALLT + tid] = bj;
    fv = best + ((tid < TAGS) ? fcur : NEGV);
    fcur = fnext;
  }
  float term = (tid < ALLT) ? (fv + trans[STOP_T * ALLT + tid]) : -1e30f;
  int idx = tid;
#pragma unroll
  for (int off = 32; off > 0; off >>= 1) {
    float v2 = __shfl_xor(term, off);
    int i2 = __shfl_xor(idx, off);
    if (v2 > term || (v2 == term && i2 < idx)) { term = v2; idx = i2; }
  }
  if (tid == 0) out[0] = term;
  int tag = __shfl(idx, 0);
  __shared__ int lbp[64 * ALLT];
  for (int T0 = S_LEN - 64; T0 >= 0; T0 -= 64) {
    for (int i = tid; i < 64 * ALLT; i += 64) lbp[i] = bp_g[(size_t)T0 * ALLT + i];
    __syncthreads();
    if (tid == 0) {
      for (int i = 63; i >= 0; --i) {
        int t = T0 + i;
        out[1 + t] = (float)tag;           // best_path[t]
        if (t > 0) tag = lbp[i * ALLT + tag];
      }
    }
    __syncthreads();
  }
}

// ---------------------------------------------------------------------------
extern "C" void kernel_launch(void* const* d_in, const int* in_sizes, int n_in,
                              void* d_out, int out_size, void* d_ws, size_t ws_size,
                              hipStream_t stream) {
  (void)in_sizes; (void)n_in; (void)out_size; (void)ws_size;
  const int*   sent  = (const int*)d_in[0];
  // d_in[1] = lengths (unused)
  const float* emb   = (const float*)d_in[2];
  const float* Wih_f = (const float*)d_in[3];
  const float* Whh_f = (const float*)d_in[4];
  const float* bih_f = (const float*)d_in[5];
  const float* bhh_f = (const float*)d_in[6];
  const float* Wih_b = (const float*)d_in[7];
  const float* Whh_b = (const float*)d_in[8];
  const float* bih_b = (const float*)d_in[9];
  const float* bhh_b = (const float*)d_in[10];
  const float* Wtag  = (const float*)d_in[11];
  const float* btag  = (const float*)d_in[12];
  const float* trans = (const float*)d_in[13];
  const float* h0    = (const float*)d_in[14];
  const float* c0    = (const float*)d_in[15];
  float* out = (float*)d_out;

  // workspace layout (bytes)
  char* ws = (char*)d_ws;
  float* Gin   = (float*)(ws);                       // 2*4096*2048*4 = 64 MiB
  float* hs    = (float*)(ws + 67108864);            // 2*4096*512*4  = 16 MiB
  float* feats = (float*)(ws + 83886080);            // 4096*32*4
  int*   bp    = (int*)  (ws + 84410368);            // 4096*34*4
  int*   flags = (int*)  (ws + 84967424);            // 2*4096*4

  hipMemsetAsync(flags, 0, 2 * S_LEN * sizeof(int), stream);

  dim3 g1(64, 64);
  ingemm_kernel<<<g1, 256, 0, stream>>>(sent, emb, Wih_f, bih_f, bhh_f,
                                        Wih_b, bih_b, bhh_b, Gin);
  lstm_kernel<<<64, 256, 0, stream>>>(Whh_f, Whh_b, h0, c0, Gin, hs, flags);
  feats_kernel<<<512, 256, 0, stream>>>(hs, Wtag, btag, feats);
  viterbi_kernel<<<1, 64, 0, stream>>>(feats, trans, bp, out);
}

// Round 2
// 16564.925 us; speedup vs baseline: 2.0253x; 2.0253x over previous
//
#include <hip/hip_runtime.h>
#include <cstdint>
#include <cstddef>

// ---------------------------------------------------------------------------
// BiLSTM-CRF (NER) for MI355X.
//   1. ingemm_kernel : Gin[dir][t][2048] = emb[sent]@Wih.T + bih + bhh
//   2. lstm_kernel   : persistent 64-WG recurrence; Whh pinned in VGPRs.
//      Sync: per-producer BYTE flags (release store; no threadfence, no RMW).
//   3. feats_kernel  : feats[t][32] = concat(hf,hb) @ W_tag.T + b_tag
//   4. Viterbi as associative max-plus block scan (B=64 blocks x L=64 steps):
//      vit_pass1: block operators P_b (parallel over 64x34 column chains)
//      vit_pass2: boundary vectors F_b (serial over 64 blocks, 1 wave)
//      vit_pass3: per-step bp + per-block backtrack maps G_b (parallel)
//      vit_echain: 64-step serial chain of G_b maps
//      vit_expand: per-block path expansion (parallel)
// ---------------------------------------------------------------------------

#define S_LEN 4096
#define E_DIM 300
#define HALF  512
#define G4    2048
#define TAGS  32
#define ALLT  34
#define START_T 32
#define STOP_T  33
#define NEGV  (-10000.0f)
#define VL    64          // viterbi steps per block
#define VB    64          // viterbi blocks

// ---------------- phase 1: embedding gather + input GEMM -------------------
#define KC 20   // 300 = 15 * 20, no tail
__global__ __launch_bounds__(256) void ingemm_kernel(
    const int* __restrict__ sent, const float* __restrict__ emb,
    const float* __restrict__ Wih_f, const float* __restrict__ bih_f, const float* __restrict__ bhh_f,
    const float* __restrict__ Wih_b, const float* __restrict__ bih_b, const float* __restrict__ bhh_b,
    float* __restrict__ Gin)
{
  __shared__ float As[64][KC + 1];
  __shared__ float Bs[64][KC + 1];
  __shared__ int sidx[64];
  const int tid = threadIdx.x;
  const int t0 = blockIdx.x * 64;
  const int J0 = blockIdx.y * 64;
  const int dir = J0 >> 11;
  const int row0 = J0 & 2047;
  const float* __restrict__ Wsrc = dir ? Wih_b : Wih_f;
  const float* __restrict__ bi = dir ? bih_b : bih_f;
  const float* __restrict__ bh = dir ? bhh_b : bhh_f;
  if (tid < 64) sidx[tid] = sent[t0 + tid];
  __syncthreads();
  float acc[4][4] = {};
  const int ty = tid >> 4, tx = tid & 15;
  for (int kk = 0; kk < E_DIM; kk += KC) {
#pragma unroll
    for (int n = 0; n < 5; ++n) {
      int idx = n * 256 + tid;
      int i = idx / KC, k = idx - i * KC;
      As[i][k] = emb[(size_t)sidx[i] * E_DIM + kk + k];
      Bs[i][k] = Wsrc[(size_t)(row0 + i) * E_DIM + kk + k];
    }
    __syncthreads();
#pragma unroll
    for (int k = 0; k < KC; ++k) {
      float a0 = As[ty * 4 + 0][k], a1 = As[ty * 4 + 1][k];
      float a2 = As[ty * 4 + 2][k], a3 = As[ty * 4 + 3][k];
      float b0 = Bs[tx * 4 + 0][k], b1 = Bs[tx * 4 + 1][k];
      float b2 = Bs[tx * 4 + 2][k], b3 = Bs[tx * 4 + 3][k];
      acc[0][0] += a0 * b0; acc[0][1] += a0 * b1; acc[0][2] += a0 * b2; acc[0][3] += a0 * b3;
      acc[1][0] += a1 * b0; acc[1][1] += a1 * b1; acc[1][2] += a1 * b2; acc[1][3] += a1 * b3;
      acc[2][0] += a2 * b0; acc[2][1] += a2 * b1; acc[2][2] += a2 * b2; acc[2][3] += a2 * b3;
      acc[3][0] += a3 * b0; acc[3][1] += a3 * b1; acc[3][2] += a3 * b2; acc[3][3] += a3 * b3;
    }
    __syncthreads();
  }
#pragma unroll
  for (int r = 0; r < 4; ++r)
#pragma unroll
    for (int cc = 0; cc < 4; ++cc) {
      int t = t0 + ty * 4 + r;
      int row = row0 + tx * 4 + cc;
      Gin[((size_t)dir * S_LEN + t) * G4 + row] = acc[r][cc] + bi[row] + bh[row];
    }
}

// ---------------- phase 2: persistent BiLSTM recurrence --------------------
// 64 WGs x 256 thr: 32 WGs/dir, each owns 16 hidden units (64 gate rows).
// Per-producer byte flags; release on flag store orders same-wave h stores.
__global__ __launch_bounds__(256, 1) void lstm_kernel(
    const float* __restrict__ Whh_f, const float* __restrict__ Whh_b,
    const float* __restrict__ h0, const float* __restrict__ c0,
    const float* __restrict__ Gin, float* __restrict__ hs,
    unsigned char* __restrict__ flagsB)
{
  const int wg = blockIdx.x;
  const int dir = wg >> 5;
  const int wgd = wg & 31;
  const int tid = threadIdx.x;
  const int wv = tid >> 6;
  const int lane = tid & 63;
  const int gate = lane >> 4;
  const int ul = lane & 15;
  const int row = gate * HALF + wgd * 16 + ul;
  const float* __restrict__ Whh = dir ? Whh_b : Whh_f;

  float w[128];
  {
    const float4* wp = (const float4*)(Whh + (size_t)row * HALF + wv * 128);
#pragma unroll
    for (int i = 0; i < 32; ++i) {
      float4 v = wp[i];
      w[4 * i + 0] = v.x; w[4 * i + 1] = v.y; w[4 * i + 2] = v.z; w[4 * i + 3] = v.w;
    }
  }

  __shared__ __align__(16) float hbuf[HALF];
  __shared__ float partial[4][64];

  float c = 0.f;
  if (tid < 16) c = c0[dir * HALF + wgd * 16 + tid];

  unsigned char* flgB = flagsB + (size_t)dir * S_LEN * 32;
  float* hs_d = hs + (size_t)dir * S_LEN * HALF;
  const float* Gin_d = Gin + (size_t)dir * S_LEN * G4;

  for (int s = 0; s < S_LEN; ++s) {
    const int t = dir ? (S_LEN - 1 - s) : s;
    // prefetch this step's Gin row (independent of h) before the flag wait
    float gin = 0.f;
    if (tid < 64) gin = Gin_d[(size_t)t * G4 + row];
    if (s > 0 && tid < 8) {
      const unsigned int* fw = (const unsigned int*)(flgB + (size_t)(s - 1) * 32);
      while (__hip_atomic_load(&fw[tid], __ATOMIC_ACQUIRE, __HIP_MEMORY_SCOPE_AGENT)
             != 0x01010101u) {}
    }
    __syncthreads();
    const float* hsrc = (s == 0) ? (h0 + dir * HALF)
                                 : (hs_d + (size_t)(dir ? t + 1 : t - 1) * HALF);
    hbuf[tid]       = __hip_atomic_load(&hsrc[tid],       __ATOMIC_RELAXED, __HIP_MEMORY_SCOPE_AGENT);
    hbuf[tid + 256] = __hip_atomic_load(&hsrc[tid + 256], __ATOMIC_RELAXED, __HIP_MEMORY_SCOPE_AGENT);
    __syncthreads();
    float a0 = 0.f, a1 = 0.f, a2 = 0.f, a3 = 0.f;
    const float4* hb4 = (const float4*)(hbuf + wv * 128);
#pragma unroll
    for (int i = 0; i < 32; ++i) {
      float4 hv = hb4[i];
      a0 += w[4 * i + 0] * hv.x;
      a1 += w[4 * i + 1] * hv.y;
      a2 += w[4 * i + 2] * hv.z;
      a3 += w[4 * i + 3] * hv.w;
    }
    partial[wv][lane] = (a0 + a1) + (a2 + a3);
    __syncthreads();
    if (tid < 64) {   // wave 0: reduce, gates, publish — no more barriers
      float g = partial[0][lane] + partial[1][lane] + partial[2][lane]
              + partial[3][lane] + gin;
      float gi = __shfl(g, ul);
      float gf = __shfl(g, 16 + ul);
      float gg = __shfl(g, 32 + ul);
      float go = __shfl(g, 48 + ul);
      if (tid < 16) {
        gi = 1.f / (1.f + __expf(-gi));
        gf = 1.f / (1.f + __expf(-gf));
        gg = 1.f - 2.f / (__expf(2.f * gg) + 1.f);   // overflow-safe tanh
        go = 1.f / (1.f + __expf(-go));
        c = gf * c + gi * gg;
        float th = 1.f - 2.f / (__expf(2.f * c) + 1.f);
        __hip_atomic_store(&hs_d[(size_t)t * HALF + wgd * 16 + tid], go * th,
                           __ATOMIC_RELAXED, __HIP_MEMORY_SCOPE_AGENT);
      }
      if (tid == 0)
        __hip_atomic_store(&flgB[(size_t)s * 32 + wgd], (unsigned char)1,
                           __ATOMIC_RELEASE, __HIP_MEMORY_SCOPE_AGENT);
    }
  }
}

// ---------------- phase 3: tag feature GEMM --------------------------------
__global__ __launch_bounds__(256) void feats_kernel(
    const float* __restrict__ hs, const float* __restrict__ Wtag,
    const float* __restrict__ btag, float* __restrict__ feats)
{
  __shared__ float hc[8][257];
  __shared__ float wt[32][257];
  const int tid = threadIdx.x;
  const int t0 = blockIdx.x * 8;
  const int lt = tid >> 5, s = tid & 31;
  float acc = 0.f;
  for (int mc = 0; mc < 1024; mc += 256) {
#pragma unroll
    for (int n = 0; n < 8; ++n) {
      int idx = n * 256 + tid;
      int r = idx >> 8, m = idx & 255;
      int gm = mc + m;
      hc[r][m] = (gm < 512) ? hs[(size_t)(t0 + r) * HALF + gm]
                            : hs[(size_t)(S_LEN + t0 + r) * HALF + (gm - 512)];
    }
#pragma unroll
    for (int n = 0; n < 32; ++n) {
      int idx = n * 256 + tid;
      int r = idx >> 8, m = idx & 255;
      wt[r][m] = Wtag[(size_t)r * 1024 + mc + m];
    }
    __syncthreads();
#pragma unroll 8
    for (int m = 0; m < 256; ++m) acc += hc[lt][m] * wt[s][m];
    __syncthreads();
  }
  feats[(size_t)(t0 + lt) * TAGS + s] = acc + btag[s];
}

// ---------------- phase 4: Viterbi (max-plus block scan) -------------------
__device__ __forceinline__ float featld(const float* __restrict__ feats, int t, int i) {
  return (i < TAGS) ? feats[(size_t)t * TAGS + i] : NEGV;
}

// pass1: P_b[:,k] = M_{bL+63} (x) ... (x) column k of M_{bL}. One wave per
// (b,k) chain; 4 chains per 256-thr WG; 2176 chains total.
__global__ __launch_bounds__(256) void vit_pass1(
    const float* __restrict__ feats, const float* __restrict__ trans,
    float* __restrict__ P)
{
  const int chain = blockIdx.x * 4 + (threadIdx.x >> 6);
  const int b = chain / ALLT;
  const int k = chain - b * ALLT;
  const int i = threadIdx.x & 63;
  float Trow[ALLT];
#pragma unroll
  for (int j = 0; j < ALLT; ++j)
    Trow[j] = (i < ALLT) ? trans[i * ALLT + j] : -1e30f;
  const int t0 = b * VL;
  float v = (i < ALLT) ? Trow[k] + featld(feats, t0, i) : -1e30f;
  float fn = featld(feats, t0 + 1, i);
  for (int idx = 1; idx < VL; ++idx) {
    float fcur = fn;
    fn = (idx < VL - 1) ? featld(feats, t0 + idx + 1, i) : 0.f;
    float m = -3.4e38f;
#pragma unroll
    for (int j = 0; j < ALLT; ++j) m = fmaxf(m, __shfl(v, j) + Trow[j]);
    v = (i < ALLT) ? m + fcur : -1e30f;
  }
  if (i < ALLT) P[((size_t)b * ALLT + i) * ALLT + k] = v;
}

// pass2: F_{b+1} = P_b (x) F_b, serial over 64 blocks, one wave.
__global__ __launch_bounds__(64) void vit_pass2(
    const float* __restrict__ P, float* __restrict__ Fb)
{
  const int i = threadIdx.x;
  float F = (i == START_T) ? 0.f : ((i < ALLT) ? NEGV : -1e30f);
  for (int b = 0; b < VB; ++b) {
    if (i < ALLT) Fb[b * ALLT + i] = F;
    float pr[ALLT];
#pragma unroll
    for (int j = 0; j < ALLT; ++j)
      pr[j] = (i < ALLT) ? P[((size_t)b * ALLT + i) * ALLT + j] : -1e30f;
    float m = -3.4e38f;
#pragma unroll
    for (int j = 0; j < ALLT; ++j) m = fmaxf(m, pr[j] + __shfl(F, j));
    F = (i < ALLT) ? m : -1e30f;
  }
}

// pass3: per block, regenerate fv_t from F_b; emit bp_t and block backtrack
// map G_b; block 63 computes terminal score + last tag.
__global__ __launch_bounds__(64) void vit_pass3(
    const float* __restrict__ feats, const float* __restrict__ trans,
    const float* __restrict__ Fb, int* __restrict__ bp, int* __restrict__ Gmap,
    float* __restrict__ out, int* __restrict__ lastT)
{
  const int b = blockIdx.x;
  const int i = threadIdx.x;
  float Trow[ALLT];
#pragma unroll
  for (int j = 0; j < ALLT; ++j)
    Trow[j] = (i < ALLT) ? trans[i * ALLT + j] : -1e30f;
  float fv = (i < ALLT) ? Fb[b * ALLT + i] : -1e30f;
  int G = 0;
  const int t0 = b * VL;
  float fn = featld(feats, t0, i);
  for (int idx = 0; idx < VL; ++idx) {
    const int t = t0 + idx;
    float fcur = fn;
    fn = (idx < VL - 1) ? featld(feats, t + 1, i) : 0.f;
    float best = -3.4e38f; int bj = 0;
#pragma unroll
    for (int j = 0; j < ALLT; ++j) {
      float sc = __shfl(fv, j) + Trow[j];
      if (sc > best) { best = sc; bj = j; }     // first-max, matches jnp.argmax
    }
    if (i < ALLT) bp[(size_t)t * ALLT + i] = bj;
    int bjc = (i < ALLT) ? bj : 0;
    G = (idx == 0) ? bjc : __shfl(G, bjc);      // G_new[g] = G_old[bp_t[g]]
    fv = (i < ALLT) ? best + fcur : -1e30f;
  }
  if (i < ALLT) Gmap[b * ALLT + i] = G;
  if (b == VB - 1) {
    float term = (i < ALLT) ? fv + trans[STOP_T * ALLT + i] : -3.4e38f;
    int idxl = i;
#pragma unroll
    for (int off = 32; off > 0; off >>= 1) {
      float v2 = __shfl_xor(term, off);
      int i2 = __shfl_xor(idxl, off);
      if (v2 > term || (v2 == term && i2 < idxl)) { term = v2; idxl = i2; }
    }
    if (i == 0) { out[0] = term; *lastT = idxl; }
  }
}

// echain: e[63]=lastT; e[b-1] = G_b[e[b]]  (64-step serial chain, one WG)
__global__ __launch_bounds__(64) void vit_echain(
    const int* __restrict__ Gmap, const int* __restrict__ lastT,
    int* __restrict__ eb)
{
  __shared__ int sG[VB * ALLT];
  for (int idx = threadIdx.x; idx < VB * ALLT; idx += 64) sG[idx] = Gmap[idx];
  __syncthreads();
  if (threadIdx.x == 0) {
    int tag = *lastT;
    eb[VB - 1] = tag;
    for (int b = VB - 1; b > 0; --b) { tag = sG[b * ALLT + tag]; eb[b - 1] = tag; }
  }
}

// expand: per block, walk bps down from e_b emitting the path.
__global__ __launch_bounds__(64) void vit_expand(
    const int* __restrict__ bp, const int* __restrict__ eb,
    float* __restrict__ out)
{
  const int b = blockIdx.x;
  __shared__ int lbp[VL * ALLT];
  for (int idx = threadIdx.x; idx < VL * ALLT; idx += 64)
    lbp[idx] = bp[(size_t)b * VL * ALLT + idx];
  __syncthreads();
  if (threadIdx.x == 0) {
    int tag = eb[b];
    for (int i = VL - 1; i >= 0; --i) {
      out[1 + b * VL + i] = (float)tag;
      tag = lbp[i * ALLT + tag];
    }
  }
}

// ---------------------------------------------------------------------------
extern "C" void kernel_launch(void* const* d_in, const int* in_sizes, int n_in,
                              void* d_out, int out_size, void* d_ws, size_t ws_size,
                              hipStream_t stream) {
  (void)in_sizes; (void)n_in; (void)out_size; (void)ws_size;
  const int*   sent  = (const int*)d_in[0];
  const float* emb   = (const float*)d_in[2];
  const float* Wih_f = (const float*)d_in[3];
  const float* Whh_f = (const float*)d_in[4];
  const float* bih_f = (const float*)d_in[5];
  const float* bhh_f = (const float*)d_in[6];
  const float* Wih_b = (const float*)d_in[7];
  const float* Whh_b = (const float*)d_in[8];
  const float* bih_b = (const float*)d_in[9];
  const float* bhh_b = (const float*)d_in[10];
  const float* Wtag  = (const float*)d_in[11];
  const float* btag  = (const float*)d_in[12];
  const float* trans = (const float*)d_in[13];
  const float* h0    = (const float*)d_in[14];
  const float* c0    = (const float*)d_in[15];
  float* out = (float*)d_out;

  // workspace layout; viterbi scratch aliases regions that are dead by the
  // time it runs (stream-ordered): P/Fb/Gmap/eb/lastT live in Gin space
  // (last read by lstm_kernel); bp aliases flags (last read by lstm_kernel).
  char* ws = (char*)d_ws;
  float* Gin   = (float*)(ws);                       // 64 MiB
  float* P     = (float*)(ws);                       // 64*34*34*4 = 295936
  float* Fbnd  = (float*)(ws + 1048576);             // 8704
  int*   Gmap  = (int*)  (ws + 2097152);             // 8704
  int*   eb    = (int*)  (ws + 3145728);             // 256
  int*   lastT = (int*)  (ws + 3146240);             // 4
  float* hs    = (float*)(ws + 67108864);            // 16 MiB
  float* feats = (float*)(ws + 83886080);            // 512 KiB
  unsigned char* flagsB = (unsigned char*)(ws + 84410368);  // 256 KiB
  int*   bp    = (int*)  (ws + 84410368);            // 557056 (aliases flags)

  hipMemsetAsync(flagsB, 0, 2 * S_LEN * 32, stream);

  dim3 g1(64, 64);
  ingemm_kernel<<<g1, 256, 0, stream>>>(sent, emb, Wih_f, bih_f, bhh_f,
                                        Wih_b, bih_b, bhh_b, Gin);
  lstm_kernel<<<64, 256, 0, stream>>>(Whh_f, Whh_b, h0, c0, Gin, hs, flagsB);
  feats_kernel<<<512, 256, 0, stream>>>(hs, Wtag, btag, feats);
  vit_pass1<<<544, 256, 0, stream>>>(feats, trans, P);
  vit_pass2<<<1, 64, 0, stream>>>(P, Fbnd);
  vit_pass3<<<64, 64, 0, stream>>>(feats, trans, Fbnd, bp, Gmap, out, lastT);
  vit_echain<<<1, 64, 0, stream>>>(Gmap, lastT, eb);
  vit_expand<<<64, 64, 0, stream>>>(bp, eb, out);
}